// Round 13
// baseline (394.854 us; speedup 1.0000x reference)
//
#include <hip/hip_runtime.h>
#include <hip/hip_fp16.h>

// ---------------------------------------------------------------------------
// LinkPredictionGNN: 2x GCNConv (self-loops, sym-norm) + pair MLP head.
//   K1 prep_w (+zero gcnt/gcur)   K2 gemm1(unscaled) UNION hist
//   K3 multisplit   K4 bucket_build
//   K5 agg1 (applies dinv[src]+dinv[dst])   K6 gemm2_f16   K7 agg2
//   K8 gemm_dual_f16   K9 pairs
//
// R1/R4: random 4B global writes/atomics -> ~10x line-writeback amp; spatial
//   XCD-affinity tricks regress. R6/R7: column-sliced gather fails; XCD L2
//   locality is not schedulable from HIP.
// R5: CSR build = 2-level bucket sort, zero global random atomics.
// R8: fp32 gemm X-tile staged via coalesced float2->LDS.
// R9/R11: agg gather at its floor (~155MB L2-miss, ~3TB/s random-256B path);
//   wider lanes don't help. Attack traffic volume instead.
// R12: fp16 intermediates h1/h2 (halve agg writes + gemm2/dual reads);
//   conv2/head GEMMs use 2-MFMA f16 path (A fp16-exact x double-f16 B),
//   no LDS (A-loads are full-line); gemm1 drops rowscale (dinv[src] applied
//   in agg1 as wave-uniform load) -> gemm1 fused with hist (R10 fusion,
//   now with correct ordering: gemm1 no longer reads dinv).
// R2: fp16 message/A/B tables (absmax budget ~6e-4 < 1.5e-3 threshold).
// R3: gemm1 (fp32 input) keeps double-bf16-split MFMA (Ah.Bh+Al.Bh+Ah.Bl).
// ---------------------------------------------------------------------------

#define BSH 9                 // log2 nodes per bucket
#define BSZ (1 << BSH)        // 512 nodes per bucket
#define MSB 4096              // edges per multisplit batch/block
#define XPAD 132              // LDS row stride (floats) for fp32 gemm staging
#define HB 256                // hist blocks in fused K2

typedef __attribute__((ext_vector_type(8))) short bf16x8;
typedef __attribute__((ext_vector_type(8))) _Float16 f16x8;
typedef __attribute__((ext_vector_type(4))) float f32x4;

__device__ __forceinline__ void acc8s(uint4 u, float f, float4& lo, float4& hi) {
  float2 f0 = __half22float2(((const __half2*)&u)[0]);
  float2 f1 = __half22float2(((const __half2*)&u)[1]);
  float2 f2 = __half22float2(((const __half2*)&u)[2]);
  float2 f3 = __half22float2(((const __half2*)&u)[3]);
  lo.x = fmaf(f, f0.x, lo.x); lo.y = fmaf(f, f0.y, lo.y);
  lo.z = fmaf(f, f1.x, lo.z); lo.w = fmaf(f, f1.y, lo.w);
  hi.x = fmaf(f, f2.x, hi.x); hi.y = fmaf(f, f2.y, hi.y);
  hi.z = fmaf(f, f3.x, hi.z); hi.w = fmaf(f, f3.y, hi.w);
}

__device__ __forceinline__ float4 h4_to_f4(uint2 u) {
  float2 fa = __half22float2(*(__half2*)&u.x);
  float2 fb = __half22float2(*(__half2*)&u.y);
  return make_float4(fa.x, fa.y, fb.x, fb.y);
}

// Exact fp32 -> bf16 hi/lo split.
__device__ __forceinline__ void split8(const float* v, bf16x8& hi, bf16x8& lo) {
#pragma unroll
  for (int j = 0; j < 8; ++j) {
    unsigned u = __float_as_uint(v[j]);
    hi[j] = (short)(u >> 16);
    float lf = v[j] - __uint_as_float(u & 0xffff0000u);
    lo[j] = (short)(__float_as_uint(lf) >> 16);
  }
}

// Weight fragments: w=0 (W1) bf16 hi/lo split (A is fp32); w=1..3 (W2, Wh1
// top/bot) f16 hi/lo split (A is fp16-exact, 2-MFMA path).
// Slot g = ((w*8+t)*4+s)*64+lane; lane holds B[k=s*32+quad*8+j][n=16t+(lane&15)]
// Block 32 zeroes gcnt/gcur (consumed by NEXT dispatch -> safe).
__global__ __launch_bounds__(256) void k_prep_w(
    const float* __restrict__ W1, const float* __restrict__ W2,
    const float* __restrict__ Wh1, short* __restrict__ fragH,
    short* __restrict__ fragL, int* __restrict__ gcnt, int* __restrict__ gcur,
    int kb) {
  if (blockIdx.x == 32) {
    int t = threadIdx.x;
    if (t < kb) { gcnt[t] = 0; gcur[t] = 0; }
    return;
  }
  int g = blockIdx.x * 256 + threadIdx.x;
  int w = g >> 11;
  int rem = g & 2047;
  int lane = rem & 63;
  int ts = rem >> 6;
  int t = ts >> 2, s = ts & 3;
  int n = (t << 4) + (lane & 15);
  int k0 = s * 32 + (lane >> 4) * 8;
  const float* W = (w == 0) ? W1 : (w == 1) ? W2 : (w == 2) ? Wh1 : (Wh1 + 128 * 128);
  short h[8], l[8];
#pragma unroll
  for (int j = 0; j < 8; ++j) {
    float x = W[(k0 + j) * 128 + n];
    if (w == 0) {
      unsigned u = __float_as_uint(x);
      h[j] = (short)(u >> 16);
      float lf = x - __uint_as_float(u & 0xffff0000u);
      l[j] = (short)(__float_as_uint(lf) >> 16);
    } else {
      __half hh = __float2half(x);
      h[j] = __half_as_short(hh);
      l[j] = __half_as_short(__float2half(x - __half2float(hh)));
    }
  }
  ((int4*)fragH)[g] = *(int4*)h;
  ((int4*)fragL)[g] = *(int4*)l;
}

// fp32-input gemm body (bf16 split, LDS-staged). NO rowscale (R12).
__device__ __forceinline__ void gemm1_body(
    const float* __restrict__ X, const short* __restrict__ fragH,
    const short* __restrict__ fragL, __half* __restrict__ C16, int n,
    int bid, float* sX) {
  int tid = threadIdx.x;
  int row0 = bid * 64;
  const float2* X2 = (const float2*)(X + (size_t)row0 * 128);
#pragma unroll
  for (int it = 0; it < 16; ++it) {
    int t = it * 256 + tid;
    int r = t >> 6, c2 = t & 63;
    int gr = row0 + r;
    float2 v = (gr < n) ? X2[t] : make_float2(0.f, 0.f);
    *(float2*)&sX[r * XPAD + c2 * 2] = v;
  }
  __syncthreads();
  int wid = tid >> 6, lane = tid & 63;
  int r0 = row0 + wid * 16;
  if (r0 >= n) return;
  int m = lane & 15, quad = lane >> 4;
  const float* xrow = sX + (wid * 16 + m) * XPAD;
  f32x4 acc[8];
#pragma unroll
  for (int t = 0; t < 8; ++t) acc[t] = (f32x4)(0.f);
  const int4* FH = (const int4*)fragH;
  const int4* FL = (const int4*)fragL;
#pragma unroll
  for (int s = 0; s < 4; ++s) {
    int k0 = s * 32 + quad * 8;
    float xv[8];
    *(float2*)&xv[0] = *(const float2*)(xrow + k0);
    *(float2*)&xv[2] = *(const float2*)(xrow + k0 + 2);
    *(float2*)&xv[4] = *(const float2*)(xrow + k0 + 4);
    *(float2*)&xv[6] = *(const float2*)(xrow + k0 + 6);
    bf16x8 ah, al;
    split8(xv, ah, al);
#pragma unroll
    for (int t = 0; t < 8; ++t) {
      int idx = (t * 4 + s) * 64 + lane;
      bf16x8 bh = *(const bf16x8*)&FH[idx];
      bf16x8 bl = *(const bf16x8*)&FL[idx];
      acc[t] = __builtin_amdgcn_mfma_f32_16x16x32_bf16(ah, bh, acc[t], 0, 0, 0);
      acc[t] = __builtin_amdgcn_mfma_f32_16x16x32_bf16(al, bh, acc[t], 0, 0, 0);
      acc[t] = __builtin_amdgcn_mfma_f32_16x16x32_bf16(ah, bl, acc[t], 0, 0, 0);
    }
  }
  // C/D layout: col = lane&15, row = quad*4 + reg
#pragma unroll
  for (int t = 0; t < 8; ++t) {
#pragma unroll
    for (int r = 0; r < 4; ++r) {
      int row = r0 + quad * 4 + r;
      C16[(size_t)row * 128 + t * 16 + m] = __float2half(acc[t][r]);
    }
  }
}

// K2: gemm1 UNION bucket-hist (both independent of CSR -> concurrent).
__global__ __launch_bounds__(256) void k_gemm_hist(
    const float* __restrict__ X, const short* __restrict__ fragH,
    const short* __restrict__ fragL, __half* __restrict__ C16, int n, int gb,
    const int* __restrict__ dst, int* __restrict__ gcnt, int e, int kb) {
  __shared__ float sX[64 * XPAD];
  if ((int)blockIdx.x < gb) {
    gemm1_body(X, fragH, fragL, C16, n, blockIdx.x, sX);
    return;
  }
  int bid = blockIdx.x - gb;
  int* h4 = (int*)sX;
  int tid = threadIdx.x, wid = tid >> 6;
  for (int t = tid; t < 512; t += 256) h4[t] = 0;
  __syncthreads();
  for (int i = bid * 256 + tid; i < e; i += HB * 256) {
    int d = __builtin_nontemporal_load(&dst[i]);
    atomicAdd(&h4[wid * 128 + (d >> BSH)], 1);
  }
  __syncthreads();
  if (tid < kb)
    atomicAdd(&gcnt[tid], h4[tid] + h4[128 + tid] + h4[256 + tid] + h4[384 + tid]);
}

// f16-input GEMM: C16 = fp16(rowscale * X16 @ W), A fp16-exact, B = f16 hi+lo
// (2 MFMAs). No LDS: A-loads are 16 rows x 64B full-line segments.
__global__ __launch_bounds__(256) void k_gemm_f16(
    const __half* __restrict__ X16, const short* __restrict__ fragH,
    const short* __restrict__ fragL, const float* __restrict__ rowscale,
    __half* __restrict__ C16, int n) {
  int wid = threadIdx.x >> 6, lane = threadIdx.x & 63;
  int r0 = (blockIdx.x * 4 + wid) * 16;
  if (r0 >= n) return;
  int m = lane & 15, quad = lane >> 4;
  const uint4* Xr = (const uint4*)(X16 + (size_t)(r0 + m) * 128);
  f32x4 acc[8];
#pragma unroll
  for (int t = 0; t < 8; ++t) acc[t] = (f32x4)(0.f);
  const int4* FH = (const int4*)fragH;
  const int4* FL = (const int4*)fragL;
#pragma unroll
  for (int s = 0; s < 4; ++s) {
    uint4 av = Xr[quad + 4 * s];
    f16x8 a = *(const f16x8*)&av;
#pragma unroll
    for (int t = 0; t < 8; ++t) {
      int idx = (t * 4 + s) * 64 + lane;
      int4 bhv = FH[idx], blv = FL[idx];
      f16x8 bh = *(const f16x8*)&bhv;
      f16x8 bl = *(const f16x8*)&blv;
      acc[t] = __builtin_amdgcn_mfma_f32_16x16x32_f16(a, bh, acc[t], 0, 0, 0);
      acc[t] = __builtin_amdgcn_mfma_f32_16x16x32_f16(a, bl, acc[t], 0, 0, 0);
    }
  }
  float sc[4];
#pragma unroll
  for (int r = 0; r < 4; ++r)
    sc[r] = rowscale ? rowscale[r0 + quad * 4 + r] : 1.f;
#pragma unroll
  for (int t = 0; t < 8; ++t) {
#pragma unroll
    for (int r = 0; r < 4; ++r) {
      int row = r0 + quad * 4 + r;
      C16[(size_t)row * 128 + t * 16 + m] = __float2half(acc[t][r] * sc[r]);
    }
  }
}

// Dual-output f16 GEMM for the head (reads X16 once; no rowscale).
__global__ __launch_bounds__(256) void k_gemm_dual_f16(
    const __half* __restrict__ X16,
    const short* __restrict__ fHa, const short* __restrict__ fLa,
    const short* __restrict__ fHb, const short* __restrict__ fLb,
    __half* __restrict__ A16, __half* __restrict__ B16, int n) {
  int wid = threadIdx.x >> 6, lane = threadIdx.x & 63;
  int r0 = (blockIdx.x * 4 + wid) * 16;
  if (r0 >= n) return;
  int m = lane & 15, quad = lane >> 4;
  const uint4* Xr = (const uint4*)(X16 + (size_t)(r0 + m) * 128);
  f32x4 accA[8], accB[8];
#pragma unroll
  for (int t = 0; t < 8; ++t) { accA[t] = (f32x4)(0.f); accB[t] = (f32x4)(0.f); }
  const int4* FHa = (const int4*)fHa; const int4* FLa = (const int4*)fLa;
  const int4* FHb = (const int4*)fHb; const int4* FLb = (const int4*)fLb;
#pragma unroll
  for (int s = 0; s < 4; ++s) {
    uint4 av = Xr[quad + 4 * s];
    f16x8 a = *(const f16x8*)&av;
#pragma unroll
    for (int t = 0; t < 8; ++t) {
      int idx = (t * 4 + s) * 64 + lane;
      int4 v0 = FHa[idx], v1 = FLa[idx], v2 = FHb[idx], v3 = FLb[idx];
      accA[t] = __builtin_amdgcn_mfma_f32_16x16x32_f16(a, *(const f16x8*)&v0, accA[t], 0, 0, 0);
      accA[t] = __builtin_amdgcn_mfma_f32_16x16x32_f16(a, *(const f16x8*)&v1, accA[t], 0, 0, 0);
      accB[t] = __builtin_amdgcn_mfma_f32_16x16x32_f16(a, *(const f16x8*)&v2, accB[t], 0, 0, 0);
      accB[t] = __builtin_amdgcn_mfma_f32_16x16x32_f16(a, *(const f16x8*)&v3, accB[t], 0, 0, 0);
    }
  }
#pragma unroll
  for (int t = 0; t < 8; ++t) {
#pragma unroll
    for (int r = 0; r < 4; ++r) {
      int row = r0 + quad * 4 + r;
      A16[(size_t)row * 128 + t * 16 + m] = __float2half(accA[t][r]);
      B16[(size_t)row * 128 + t * 16 + m] = __float2half(accB[t][r]);
    }
  }
}

// multisplit: per-wave replicated LDS hist; in-block scan of gcnt; one global
// atomic per bucket per batch. packed = (d_local<<16)|src  [src < 65536]
__global__ __launch_bounds__(256) void k_multisplit(const int* __restrict__ src,
                                                    const int* __restrict__ dst,
                                                    const int* __restrict__ gcnt,
                                                    int* __restrict__ gcur,
                                                    int* __restrict__ tmp,
                                                    int e, int kb) {
  __shared__ int h4[4 * 128], off[4 * 128], sbase[128], ws[2];
  int tid = threadIdx.x, wid = tid >> 6, lane = tid & 63;
  for (int t = tid; t < 512; t += 256) h4[t] = 0;
  __syncthreads();
  int i0 = blockIdx.x * MSB + tid;
  int d[16], rk[16];
#pragma unroll
  for (int u = 0; u < 16; ++u) {
    int i = i0 + u * 256;
    if (i < e) {
      d[u] = __builtin_nontemporal_load(&dst[i]);
      rk[u] = atomicAdd(&h4[wid * 128 + (d[u] >> BSH)], 1);
    }
  }
  __syncthreads();
  int tot = 0;
  if (tid < 128) {
    int c0 = h4[tid], c1 = h4[128 + tid], c2 = h4[256 + tid], c3 = h4[384 + tid];
    off[tid] = 0; off[128 + tid] = c0;
    off[256 + tid] = c0 + c1; off[384 + tid] = c0 + c1 + c2;
    tot = c0 + c1 + c2 + c3;
  }
  int v = (tid < 128 && tid < kb) ? gcnt[tid] : 0;
  int orig = v;
#pragma unroll
  for (int o = 1; o < 64; o <<= 1) {
    int u = __shfl_up(v, o, 64);
    if (lane >= o) v += u;
  }
  if (lane == 63 && wid < 2) ws[wid] = v;
  __syncthreads();
  if (tid < 128) sbase[tid] = ((wid == 1) ? ws[0] : 0) + v - orig;
  __syncthreads();
  if (tid < kb && tot > 0) sbase[tid] += atomicAdd(&gcur[tid], tot);
  __syncthreads();
#pragma unroll
  for (int u = 0; u < 16; ++u) {
    int i = i0 + u * 256;
    if (i < e) {
      int s = __builtin_nontemporal_load(&src[i]);
      int k = d[u] >> BSH;
      tmp[sbase[k] + off[wid * 128 + k] + rk[u]] = ((d[u] & (BSZ - 1)) << 16) | s;
    }
  }
}

// one block per bucket: in-block scan of gcnt; per-node degree + scan +
// cursor scatter in LDS. colarr u16, bucket-local (no write-amp).
__global__ __launch_bounds__(512) void k_bucket_build(
    const int* __restrict__ tmp, const int* __restrict__ gcnt,
    int* __restrict__ rowptr, float* __restrict__ dinv,
    unsigned short* __restrict__ colarr, int n, int kb, int e) {
  __shared__ int dl[BSZ], cl[BSZ], sbase[128], ws[8];
  int t = threadIdx.x, b = blockIdx.x;
  int lane = t & 63, w = t >> 6;
  int v = (t < 128 && t < kb) ? gcnt[t] : 0;
  int orig0 = v;
#pragma unroll
  for (int o = 1; o < 64; o <<= 1) {
    int u = __shfl_up(v, o, 64);
    if (lane >= o) v += u;
  }
  if (lane == 63 && w < 2) ws[w] = v;
  dl[t] = 0;
  __syncthreads();
  if (t < 128) sbase[t] = ((w == 1) ? ws[0] : 0) + v - orig0;
  __syncthreads();
  int s0 = sbase[b];
  int s1 = s0 + gcnt[b];
  for (int j = s0 + t; j < s1; j += 512)
    atomicAdd(&dl[((unsigned)tmp[j]) >> 16], 1);
  __syncthreads();
  int dv = dl[t], orig = dv;
#pragma unroll
  for (int o = 1; o < 64; o <<= 1) {
    int u = __shfl_up(dv, o, 64);
    if (lane >= o) dv += u;
  }
  if (lane == 63) ws[w] = dv;
  __syncthreads();
  if (t == 0) {
    int a = 0;
#pragma unroll
    for (int k = 0; k < 8; ++k) { int x = ws[k]; ws[k] = a; a += x; }
  }
  __syncthreads();
  int ex = ws[w] + dv - orig;
  cl[t] = ex;
  int node = (b << BSH) + t;
  if (node < n) {
    rowptr[node] = s0 + ex;
    dinv[node] = rsqrtf((float)(orig + 1));  // +1 self loop
  }
  if (b == kb - 1 && t == 0) rowptr[n] = e;
  __syncthreads();
  for (int j = s0 + t; j < s1; j += 512) {
    int p = tmp[j];
    int r = atomicAdd(&cl[((unsigned)p) >> 16], 1);
    colarr[s0 + r] = (unsigned short)(p & 0xFFFF);
  }
}

// out16[i,:] = fp16(relu(dinv[i]*(S + self) + bias)), where
//   srcscale!=null: S = sum dinv[col]*g[col], self = dinv[i]*g[i]  (conv1)
//   srcscale==null: S = sum g[col],           self = g[i]          (conv2)
// uint4 lanes: 16 lanes x 16B = 256B row; 4 edge subgroups, 4-deep unroll.
__global__ __launch_bounds__(256) void k_agg_h(
    const __half2* __restrict__ g2, const float* __restrict__ dinv,
    const float* __restrict__ srcscale,
    const int* __restrict__ rowptr, const unsigned short* __restrict__ col,
    const float* __restrict__ bias, __half* __restrict__ out16, int n) {
  int i = blockIdx.x * 4 + (threadIdx.x >> 6);
  if (i >= n) return;
  int lane = threadIdx.x & 63;
  int sub = lane >> 4;
  int c8 = lane & 15;
  const uint4* G = (const uint4*)g2;
  float di = dinv[i];
  float4 z = make_float4(0.f, 0.f, 0.f, 0.f);
  float4 lo0 = z, lo1 = z, lo2 = z, lo3 = z, hi0 = z, hi1 = z, hi2 = z, hi3 = z;
  if (sub == 0)
    acc8s(G[(size_t)i * 16 + c8], srcscale ? di : 1.f, lo0, hi0);  // self loop
  int beg = rowptr[i], end = rowptr[i + 1];
  int j = beg;
  for (; j + 16 <= end; j += 16) {
    int s0 = __builtin_nontemporal_load(&col[j + sub]);
    int s1 = __builtin_nontemporal_load(&col[j + 4 + sub]);
    int s2 = __builtin_nontemporal_load(&col[j + 8 + sub]);
    int s3 = __builtin_nontemporal_load(&col[j + 12 + sub]);
    float f0 = srcscale ? srcscale[s0] : 1.f;
    float f1 = srcscale ? srcscale[s1] : 1.f;
    float f2 = srcscale ? srcscale[s2] : 1.f;
    float f3 = srcscale ? srcscale[s3] : 1.f;
    uint4 u0 = G[(size_t)s0 * 16 + c8];
    uint4 u1 = G[(size_t)s1 * 16 + c8];
    uint4 u2 = G[(size_t)s2 * 16 + c8];
    uint4 u3 = G[(size_t)s3 * 16 + c8];
    acc8s(u0, f0, lo0, hi0); acc8s(u1, f1, lo1, hi1);
    acc8s(u2, f2, lo2, hi2); acc8s(u3, f3, lo3, hi3);
  }
  for (; j + 4 <= end; j += 4) {
    int s0 = __builtin_nontemporal_load(&col[j + sub]);
    float f0 = srcscale ? srcscale[s0] : 1.f;
    acc8s(G[(size_t)s0 * 16 + c8], f0, lo1, hi1);
  }
  int rem = end - j;
  if (sub < rem) {
    int s0 = __builtin_nontemporal_load(&col[j + sub]);
    float f0 = srcscale ? srcscale[s0] : 1.f;
    acc8s(G[(size_t)s0 * 16 + c8], f0, lo2, hi2);
  }
  float4 lo, hi;
  lo.x = (lo0.x + lo1.x) + (lo2.x + lo3.x);
  lo.y = (lo0.y + lo1.y) + (lo2.y + lo3.y);
  lo.z = (lo0.z + lo1.z) + (lo2.z + lo3.z);
  lo.w = (lo0.w + lo1.w) + (lo2.w + lo3.w);
  hi.x = (hi0.x + hi1.x) + (hi2.x + hi3.x);
  hi.y = (hi0.y + hi1.y) + (hi2.y + hi3.y);
  hi.z = (hi0.z + hi1.z) + (hi2.z + hi3.z);
  hi.w = (hi0.w + hi1.w) + (hi2.w + hi3.w);
  lo.x += __shfl_down(lo.x, 32, 64); lo.x += __shfl_down(lo.x, 16, 64);
  lo.y += __shfl_down(lo.y, 32, 64); lo.y += __shfl_down(lo.y, 16, 64);
  lo.z += __shfl_down(lo.z, 32, 64); lo.z += __shfl_down(lo.z, 16, 64);
  lo.w += __shfl_down(lo.w, 32, 64); lo.w += __shfl_down(lo.w, 16, 64);
  hi.x += __shfl_down(hi.x, 32, 64); hi.x += __shfl_down(hi.x, 16, 64);
  hi.y += __shfl_down(hi.y, 32, 64); hi.y += __shfl_down(hi.y, 16, 64);
  hi.z += __shfl_down(hi.z, 32, 64); hi.z += __shfl_down(hi.z, 16, 64);
  hi.w += __shfl_down(hi.w, 32, 64); hi.w += __shfl_down(hi.w, 16, 64);
  if (sub == 0) {
    float4 b0 = ((const float4*)bias)[2 * c8];
    float4 b1 = ((const float4*)bias)[2 * c8 + 1];
    __half2 q0 = __floats2half2_rn(fmaxf(fmaf(di, lo.x, b0.x), 0.f),
                                   fmaxf(fmaf(di, lo.y, b0.y), 0.f));
    __half2 q1 = __floats2half2_rn(fmaxf(fmaf(di, lo.z, b0.z), 0.f),
                                   fmaxf(fmaf(di, lo.w, b0.w), 0.f));
    __half2 q2 = __floats2half2_rn(fmaxf(fmaf(di, hi.x, b1.x), 0.f),
                                   fmaxf(fmaf(di, hi.y, b1.y), 0.f));
    __half2 q3 = __floats2half2_rn(fmaxf(fmaf(di, hi.z, b1.z), 0.f),
                                   fmaxf(fmaf(di, hi.w, b1.w), 0.f));
    uint4 o;
    o.x = *(unsigned*)&q0; o.y = *(unsigned*)&q1;
    o.z = *(unsigned*)&q2; o.w = *(unsigned*)&q3;
    ((uint4*)out16)[(size_t)i * 16 + c8] = o;
  }
}

// one wave per pair: sub0 loads A[p0] half4, sub1 loads B[p1] half4;
// combine via shfl_xor(32), dot with wh2, reduce.
__global__ __launch_bounds__(256) void k_pairs_h(
    const __half2* __restrict__ A, const __half2* __restrict__ B,
    const int* __restrict__ pairs, const float* __restrict__ bh1,
    const float* __restrict__ wh2, const float* __restrict__ bh2,
    float* __restrict__ out, int P) {
  int p = blockIdx.x * 4 + (threadIdx.x >> 6);
  int lane = threadIdx.x & 63;
  if (p >= P) return;
  int sub = lane >> 5, c4 = lane & 31;
  int p0 = pairs[2 * p], p1 = pairs[2 * p + 1];
  const uint2* T4 = sub ? (const uint2*)B : (const uint2*)A;
  int row = sub ? p1 : p0;
  float4 v = h4_to_f4(T4[(size_t)row * 32 + c4]);
  v.x += __shfl_xor(v.x, 32, 64);
  v.y += __shfl_xor(v.y, 32, 64);
  v.z += __shfl_xor(v.z, 32, 64);
  v.w += __shfl_xor(v.w, 32, 64);
  float4 bi = ((const float4*)bh1)[c4];
  float4 wv = ((const float4*)wh2)[c4];
  float s = fmaxf(v.x + bi.x, 0.f) * wv.x + fmaxf(v.y + bi.y, 0.f) * wv.y +
            fmaxf(v.z + bi.z, 0.f) * wv.z + fmaxf(v.w + bi.w, 0.f) * wv.w;
#pragma unroll
  for (int o = 16; o > 0; o >>= 1) s += __shfl_down(s, o, 64);
  if (lane == 0) out[p] = s + bh2[0];
}

extern "C" void kernel_launch(void* const* d_in, const int* in_sizes, int n_in,
                              void* d_out, int out_size, void* d_ws, size_t ws_size,
                              hipStream_t stream) {
  const float* x   = (const float*)d_in[0];
  const int* ei    = (const int*)d_in[1];
  const int* pairs = (const int*)d_in[2];
  const float* W1  = (const float*)d_in[3];
  const float* b1  = (const float*)d_in[4];
  const float* W2  = (const float*)d_in[5];
  const float* b2  = (const float*)d_in[6];
  const float* Wh1 = (const float*)d_in[7];
  const float* bh1 = (const float*)d_in[8];
  const float* Wh2 = (const float*)d_in[9];
  const float* bh2 = (const float*)d_in[10];
  (void)n_in; (void)out_size; (void)ws_size;

  int N = in_sizes[0] / 128;
  int E = in_sizes[1] / 2;
  int P = in_sizes[2] / 2;
  const int* src = ei;
  const int* dst = ei + E;
  int KB = (N + BSZ - 1) >> BSH;  // buckets (98 for N=50000)

  char* wsp = (char*)d_ws;
  size_t off = 0;
  auto alloc = [&](size_t bytes) -> void* {
    void* p = wsp + off;
    off += (bytes + 255) & ~(size_t)255;
    return p;
  };
  __half* g16 = (__half*)alloc((size_t)N * 128 * 2);  // messages; reused as A16
  __half* h1  = (__half*)alloc((size_t)N * 128 * 2);  // fp16; reused as B16
  __half* h2  = (__half*)alloc((size_t)N * 128 * 2);  // fp16
  float* dinv = (float*)alloc((size_t)N * 4);
  int* rowptr = (int*)alloc((size_t)(N + 1) * 4);
  unsigned short* colarr = (unsigned short*)alloc((size_t)E * 2);
  int* tmp    = (int*)alloc((size_t)E * 4);
  short* fragH = (short*)alloc(4 * 2048 * 8 * 2);     // 128KB
  short* fragL = (short*)alloc(4 * 2048 * 8 * 2);     // 128KB
  int* gcnt  = (int*)alloc((size_t)(KB + 1) * 4);
  int* gcur  = (int*)alloc((size_t)(KB + 1) * 4);
  __half* A16 = g16;            // g16 dead by the time head runs
  __half* B16 = h1;             // h1 dead after conv2 gemm
  short* fH_W1 = fragH + 0 * 16384;  short* fL_W1 = fragL + 0 * 16384;
  short* fH_W2 = fragH + 1 * 16384;  short* fL_W2 = fragL + 1 * 16384;
  short* fH_Wa = fragH + 2 * 16384;  short* fL_Wa = fragL + 2 * 16384;
  short* fH_Wb = fragH + 3 * 16384;  short* fL_Wb = fragL + 3 * 16384;

  int GB = (N + 63) / 64;          // fp32 gemm: 64 rows per block
  int GF = (N / 16 + 3) / 4;       // f16 gemm: 16 rows/wave, 4 waves/block
  int AB = (N + 3) / 4;            // agg: 4 rows per block

  // K1: weight frags (+zero gcnt/gcur in block 32)
  k_prep_w<<<33, 256, 0, stream>>>(W1, W2, Wh1, fragH, fragL, gcnt, gcur, KB);
  // K2: gemm1 (unscaled) UNION bucket hist
  k_gemm_hist<<<GB + HB, 256, 0, stream>>>(x, fH_W1, fL_W1, g16, N, GB,
                                           dst, gcnt, E, KB);
  // K3..K4: CSR build
  k_multisplit<<<(E + MSB - 1) / MSB, 256, 0, stream>>>(src, dst, gcnt, gcur,
                                                        tmp, E, KB);
  k_bucket_build<<<KB, 512, 0, stream>>>(tmp, gcnt, rowptr, dinv, colarr, N, KB, E);
  // K5: agg1 (applies dinv[src] per edge and dinv[i] on self/post)
  k_agg_h<<<AB, 256, 0, stream>>>((const __half2*)g16, dinv, dinv, rowptr,
                                  colarr, b1, h1, N);
  // K6: conv2 gemm (f16 path, rowscale=dinv)
  k_gemm_f16<<<GF, 256, 0, stream>>>(h1, fH_W2, fL_W2, dinv, g16, N);
  // K7: agg2 (g16 already scaled)
  k_agg_h<<<AB, 256, 0, stream>>>((const __half2*)g16, dinv, nullptr, rowptr,
                                  colarr, b2, h2, N);
  // K8: head dual gemm (f16)
  k_gemm_dual_f16<<<GF, 256, 0, stream>>>(h2, fH_Wa, fL_Wa, fH_Wb, fL_Wb,
                                          A16, B16, N);
  // K9: pairs
  k_pairs_h<<<(P + 3) / 4, 256, 0, stream>>>((const __half2*)A16, (const __half2*)B16,
                                             pairs, bh1, Wh2, bh2, (float*)d_out, P);
}

// Round 14
// 370.851 us; speedup vs baseline: 1.0647x; 1.0647x over previous
//
#include <hip/hip_runtime.h>
#include <hip/hip_fp16.h>

// ---------------------------------------------------------------------------
// LinkPredictionGNN: 2x GCNConv (self-loops, sym-norm) + pair MLP head.
//   memset gcnt/gcur -> K1 prep_w UNION hist -> K2 multisplit -> K3 bucket
//   K4 gemm1 (fp32 x, bf16-split, rowscale=dinv) -> K5 agg1 (fp16 out)
//   K6 gemm2_f16 -> K7 agg2 -> K8 gemm_dual_f16 -> K9 pairs
//
// R1/R4: random 4B global writes/atomics -> ~10x line-writeback amp; spatial
//   XCD-affinity tricks regress. R6/R7: column-sliced gather fails.
// R5: CSR build = 2-level bucket sort, zero global random atomics.
// R8: fp32 gemm X-tile staged via coalesced float2->LDS.
// R9/R11: agg gather at its floor (~155MB L2-miss); wider lanes don't help.
// R12 FAILED: per-edge dinv[src] select in agg broke load pipelining
//   (agg 61->84us, VALUBusy 37->30). R13: normalization back in gemm1
//   epilogue (R11 placement); agg loop clean again. KEPT from R12: fp16
//   h1/h2 (halves agg writes), f16 2-MFMA GEMM for conv2/head, and a LEGAL
//   fusion: hist UNION prep_w after hipMemsetAsync zeroing of gcnt/gcur.
// R2: fp16 message/A/B tables (absmax 4.9e-4 < 1.5e-3 threshold).
// R3: gemm1 (fp32 input) double-bf16-split MFMA (Ah.Bh+Al.Bh+Ah.Bl).
// ---------------------------------------------------------------------------

#define BSH 9                 // log2 nodes per bucket
#define BSZ (1 << BSH)        // 512 nodes per bucket
#define MSB 4096              // edges per multisplit batch/block
#define XPAD 132              // LDS row stride (floats) for fp32 gemm staging
#define HB 256                // hist blocks in fused K1

typedef __attribute__((ext_vector_type(8))) short bf16x8;
typedef __attribute__((ext_vector_type(8))) _Float16 f16x8;
typedef __attribute__((ext_vector_type(4))) float f32x4;

__device__ __forceinline__ void acc8(uint4 u, float4& lo, float4& hi) {
  float2 f0 = __half22float2(((const __half2*)&u)[0]);
  float2 f1 = __half22float2(((const __half2*)&u)[1]);
  float2 f2 = __half22float2(((const __half2*)&u)[2]);
  float2 f3 = __half22float2(((const __half2*)&u)[3]);
  lo.x += f0.x; lo.y += f0.y; lo.z += f1.x; lo.w += f1.y;
  hi.x += f2.x; hi.y += f2.y; hi.z += f3.x; hi.w += f3.y;
}

__device__ __forceinline__ float4 h4_to_f4(uint2 u) {
  float2 fa = __half22float2(*(__half2*)&u.x);
  float2 fb = __half22float2(*(__half2*)&u.y);
  return make_float4(fa.x, fa.y, fb.x, fb.y);
}

// Exact fp32 -> bf16 hi/lo split.
__device__ __forceinline__ void split8(const float* v, bf16x8& hi, bf16x8& lo) {
#pragma unroll
  for (int j = 0; j < 8; ++j) {
    unsigned u = __float_as_uint(v[j]);
    hi[j] = (short)(u >> 16);
    float lf = v[j] - __uint_as_float(u & 0xffff0000u);
    lo[j] = (short)(__float_as_uint(lf) >> 16);
  }
}

// K1: weight fragment prep UNION dst bucket-histogram (both CSR-independent;
// gcnt/gcur pre-zeroed by hipMemsetAsync).
// Frags: w=0 (W1) bf16 hi/lo (A fp32); w=1..3 f16 hi/lo (A fp16-exact).
// Slot g = ((w*8+t)*4+s)*64+lane; lane holds B[k=s*32+quad*8+j][n=16t+(lane&15)]
__global__ __launch_bounds__(256) void k_prep_hist(
    const float* __restrict__ W1, const float* __restrict__ W2,
    const float* __restrict__ Wh1, short* __restrict__ fragH,
    short* __restrict__ fragL,
    const int* __restrict__ dst, int* __restrict__ gcnt, int e, int kb) {
  if (blockIdx.x >= 32) {
    __shared__ int h4[512];
    int bid = blockIdx.x - 32;
    int tid = threadIdx.x, wid = tid >> 6;
    for (int t = tid; t < 512; t += 256) h4[t] = 0;
    __syncthreads();
    for (int i = bid * 256 + tid; i < e; i += HB * 256) {
      int d = __builtin_nontemporal_load(&dst[i]);
      atomicAdd(&h4[wid * 128 + (d >> BSH)], 1);
    }
    __syncthreads();
    if (tid < kb)
      atomicAdd(&gcnt[tid], h4[tid] + h4[128 + tid] + h4[256 + tid] + h4[384 + tid]);
    return;
  }
  int g = blockIdx.x * 256 + threadIdx.x;
  int w = g >> 11;
  int rem = g & 2047;
  int lane = rem & 63;
  int ts = rem >> 6;
  int t = ts >> 2, s = ts & 3;
  int n = (t << 4) + (lane & 15);
  int k0 = s * 32 + (lane >> 4) * 8;
  const float* W = (w == 0) ? W1 : (w == 1) ? W2 : (w == 2) ? Wh1 : (Wh1 + 128 * 128);
  short h[8], l[8];
#pragma unroll
  for (int j = 0; j < 8; ++j) {
    float x = W[(k0 + j) * 128 + n];
    if (w == 0) {
      unsigned u = __float_as_uint(x);
      h[j] = (short)(u >> 16);
      float lf = x - __uint_as_float(u & 0xffff0000u);
      l[j] = (short)(__float_as_uint(lf) >> 16);
    } else {
      __half hh = __float2half(x);
      h[j] = __half_as_short(hh);
      l[j] = __half_as_short(__float2half(x - __half2float(hh)));
    }
  }
  ((int4*)fragH)[g] = *(int4*)h;
  ((int4*)fragL)[g] = *(int4*)l;
}

// fp32-input MFMA GEMM: C16 = fp16(rowscale * X@W1), bf16 split, LDS-staged.
__global__ __launch_bounds__(256) void k_gemm_mfma(
    const float* __restrict__ X, const short* __restrict__ fragH,
    const short* __restrict__ fragL, const float* __restrict__ rowscale,
    __half* __restrict__ C16, int n) {
  __shared__ float sX[64 * XPAD];
  int tid = threadIdx.x;
  int row0 = blockIdx.x * 64;
  const float2* X2 = (const float2*)(X + (size_t)row0 * 128);
#pragma unroll
  for (int it = 0; it < 16; ++it) {
    int t = it * 256 + tid;
    int r = t >> 6, c2 = t & 63;
    int gr = row0 + r;
    float2 v = (gr < n) ? X2[t] : make_float2(0.f, 0.f);
    *(float2*)&sX[r * XPAD + c2 * 2] = v;
  }
  __syncthreads();
  int wid = tid >> 6, lane = tid & 63;
  int r0 = row0 + wid * 16;
  if (r0 >= n) return;
  int m = lane & 15, quad = lane >> 4;
  const float* xrow = sX + (wid * 16 + m) * XPAD;
  f32x4 acc[8];
#pragma unroll
  for (int t = 0; t < 8; ++t) acc[t] = (f32x4)(0.f);
  const int4* FH = (const int4*)fragH;
  const int4* FL = (const int4*)fragL;
#pragma unroll
  for (int s = 0; s < 4; ++s) {
    int k0 = s * 32 + quad * 8;
    float xv[8];
    *(float2*)&xv[0] = *(const float2*)(xrow + k0);
    *(float2*)&xv[2] = *(const float2*)(xrow + k0 + 2);
    *(float2*)&xv[4] = *(const float2*)(xrow + k0 + 4);
    *(float2*)&xv[6] = *(const float2*)(xrow + k0 + 6);
    bf16x8 ah, al;
    split8(xv, ah, al);
#pragma unroll
    for (int t = 0; t < 8; ++t) {
      int idx = (t * 4 + s) * 64 + lane;
      bf16x8 bh = *(const bf16x8*)&FH[idx];
      bf16x8 bl = *(const bf16x8*)&FL[idx];
      acc[t] = __builtin_amdgcn_mfma_f32_16x16x32_bf16(ah, bh, acc[t], 0, 0, 0);
      acc[t] = __builtin_amdgcn_mfma_f32_16x16x32_bf16(al, bh, acc[t], 0, 0, 0);
      acc[t] = __builtin_amdgcn_mfma_f32_16x16x32_bf16(ah, bl, acc[t], 0, 0, 0);
    }
  }
  // C/D layout: col = lane&15, row = quad*4 + reg   [m89-verified]
  float sc[4];
#pragma unroll
  for (int r = 0; r < 4; ++r)
    sc[r] = rowscale[r0 + quad * 4 + r];
#pragma unroll
  for (int t = 0; t < 8; ++t) {
#pragma unroll
    for (int r = 0; r < 4; ++r) {
      int row = r0 + quad * 4 + r;
      C16[(size_t)row * 128 + t * 16 + m] = __float2half(acc[t][r] * sc[r]);
    }
  }
}

// f16-input GEMM: C16 = fp16(rowscale * X16 @ W), A fp16-exact, B = f16 hi+lo
// (2 MFMAs). No LDS: A-loads are 16 rows x 64B full-line segments.
__global__ __launch_bounds__(256) void k_gemm_f16(
    const __half* __restrict__ X16, const short* __restrict__ fragH,
    const short* __restrict__ fragL, const float* __restrict__ rowscale,
    __half* __restrict__ C16, int n) {
  int wid = threadIdx.x >> 6, lane = threadIdx.x & 63;
  int r0 = (blockIdx.x * 4 + wid) * 16;
  if (r0 >= n) return;
  int m = lane & 15, quad = lane >> 4;
  const uint4* Xr = (const uint4*)(X16 + (size_t)(r0 + m) * 128);
  f32x4 acc[8];
#pragma unroll
  for (int t = 0; t < 8; ++t) acc[t] = (f32x4)(0.f);
  const int4* FH = (const int4*)fragH;
  const int4* FL = (const int4*)fragL;
#pragma unroll
  for (int s = 0; s < 4; ++s) {
    uint4 av = Xr[quad + 4 * s];
    f16x8 a = *(const f16x8*)&av;
#pragma unroll
    for (int t = 0; t < 8; ++t) {
      int idx = (t * 4 + s) * 64 + lane;
      int4 bhv = FH[idx], blv = FL[idx];
      f16x8 bh = *(const f16x8*)&bhv;
      f16x8 bl = *(const f16x8*)&blv;
      acc[t] = __builtin_amdgcn_mfma_f32_16x16x32_f16(a, bh, acc[t], 0, 0, 0);
      acc[t] = __builtin_amdgcn_mfma_f32_16x16x32_f16(a, bl, acc[t], 0, 0, 0);
    }
  }
  float sc[4];
#pragma unroll
  for (int r = 0; r < 4; ++r)
    sc[r] = rowscale ? rowscale[r0 + quad * 4 + r] : 1.f;
#pragma unroll
  for (int t = 0; t < 8; ++t) {
#pragma unroll
    for (int r = 0; r < 4; ++r) {
      int row = r0 + quad * 4 + r;
      C16[(size_t)row * 128 + t * 16 + m] = __float2half(acc[t][r] * sc[r]);
    }
  }
}

// Dual-output f16 GEMM for the head (reads X16 once; no rowscale).
__global__ __launch_bounds__(256) void k_gemm_dual_f16(
    const __half* __restrict__ X16,
    const short* __restrict__ fHa, const short* __restrict__ fLa,
    const short* __restrict__ fHb, const short* __restrict__ fLb,
    __half* __restrict__ A16, __half* __restrict__ B16, int n) {
  int wid = threadIdx.x >> 6, lane = threadIdx.x & 63;
  int r0 = (blockIdx.x * 4 + wid) * 16;
  if (r0 >= n) return;
  int m = lane & 15, quad = lane >> 4;
  const uint4* Xr = (const uint4*)(X16 + (size_t)(r0 + m) * 128);
  f32x4 accA[8], accB[8];
#pragma unroll
  for (int t = 0; t < 8; ++t) { accA[t] = (f32x4)(0.f); accB[t] = (f32x4)(0.f); }
  const int4* FHa = (const int4*)fHa; const int4* FLa = (const int4*)fLa;
  const int4* FHb = (const int4*)fHb; const int4* FLb = (const int4*)fLb;
#pragma unroll
  for (int s = 0; s < 4; ++s) {
    uint4 av = Xr[quad + 4 * s];
    f16x8 a = *(const f16x8*)&av;
#pragma unroll
    for (int t = 0; t < 8; ++t) {
      int idx = (t * 4 + s) * 64 + lane;
      int4 v0 = FHa[idx], v1 = FLa[idx], v2 = FHb[idx], v3 = FLb[idx];
      accA[t] = __builtin_amdgcn_mfma_f32_16x16x32_f16(a, *(const f16x8*)&v0, accA[t], 0, 0, 0);
      accA[t] = __builtin_amdgcn_mfma_f32_16x16x32_f16(a, *(const f16x8*)&v1, accA[t], 0, 0, 0);
      accB[t] = __builtin_amdgcn_mfma_f32_16x16x32_f16(a, *(const f16x8*)&v2, accB[t], 0, 0, 0);
      accB[t] = __builtin_amdgcn_mfma_f32_16x16x32_f16(a, *(const f16x8*)&v3, accB[t], 0, 0, 0);
    }
  }
#pragma unroll
  for (int t = 0; t < 8; ++t) {
#pragma unroll
    for (int r = 0; r < 4; ++r) {
      int row = r0 + quad * 4 + r;
      A16[(size_t)row * 128 + t * 16 + m] = __float2half(accA[t][r]);
      B16[(size_t)row * 128 + t * 16 + m] = __float2half(accB[t][r]);
    }
  }
}

// multisplit: per-wave replicated LDS hist; in-block scan of gcnt; one global
// atomic per bucket per batch. packed = (d_local<<16)|src  [src < 65536]
__global__ __launch_bounds__(256) void k_multisplit(const int* __restrict__ src,
                                                    const int* __restrict__ dst,
                                                    const int* __restrict__ gcnt,
                                                    int* __restrict__ gcur,
                                                    int* __restrict__ tmp,
                                                    int e, int kb) {
  __shared__ int h4[4 * 128], off[4 * 128], sbase[128], ws[2];
  int tid = threadIdx.x, wid = tid >> 6, lane = tid & 63;
  for (int t = tid; t < 512; t += 256) h4[t] = 0;
  __syncthreads();
  int i0 = blockIdx.x * MSB + tid;
  int d[16], rk[16];
#pragma unroll
  for (int u = 0; u < 16; ++u) {
    int i = i0 + u * 256;
    if (i < e) {
      d[u] = __builtin_nontemporal_load(&dst[i]);
      rk[u] = atomicAdd(&h4[wid * 128 + (d[u] >> BSH)], 1);
    }
  }
  __syncthreads();
  int tot = 0;
  if (tid < 128) {
    int c0 = h4[tid], c1 = h4[128 + tid], c2 = h4[256 + tid], c3 = h4[384 + tid];
    off[tid] = 0; off[128 + tid] = c0;
    off[256 + tid] = c0 + c1; off[384 + tid] = c0 + c1 + c2;
    tot = c0 + c1 + c2 + c3;
  }
  int v = (tid < 128 && tid < kb) ? gcnt[tid] : 0;
  int orig = v;
#pragma unroll
  for (int o = 1; o < 64; o <<= 1) {
    int u = __shfl_up(v, o, 64);
    if (lane >= o) v += u;
  }
  if (lane == 63 && wid < 2) ws[wid] = v;
  __syncthreads();
  if (tid < 128) sbase[tid] = ((wid == 1) ? ws[0] : 0) + v - orig;
  __syncthreads();
  if (tid < kb && tot > 0) sbase[tid] += atomicAdd(&gcur[tid], tot);
  __syncthreads();
#pragma unroll
  for (int u = 0; u < 16; ++u) {
    int i = i0 + u * 256;
    if (i < e) {
      int s = __builtin_nontemporal_load(&src[i]);
      int k = d[u] >> BSH;
      tmp[sbase[k] + off[wid * 128 + k] + rk[u]] = ((d[u] & (BSZ - 1)) << 16) | s;
    }
  }
}

// one block per bucket: in-block scan of gcnt; per-node degree + scan +
// cursor scatter in LDS. colarr u16, bucket-local (no write-amp).
__global__ __launch_bounds__(512) void k_bucket_build(
    const int* __restrict__ tmp, const int* __restrict__ gcnt,
    int* __restrict__ rowptr, float* __restrict__ dinv,
    unsigned short* __restrict__ colarr, int n, int kb, int e) {
  __shared__ int dl[BSZ], cl[BSZ], sbase[128], ws[8];
  int t = threadIdx.x, b = blockIdx.x;
  int lane = t & 63, w = t >> 6;
  int v = (t < 128 && t < kb) ? gcnt[t] : 0;
  int orig0 = v;
#pragma unroll
  for (int o = 1; o < 64; o <<= 1) {
    int u = __shfl_up(v, o, 64);
    if (lane >= o) v += u;
  }
  if (lane == 63 && w < 2) ws[w] = v;
  dl[t] = 0;
  __syncthreads();
  if (t < 128) sbase[t] = ((w == 1) ? ws[0] : 0) + v - orig0;
  __syncthreads();
  int s0 = sbase[b];
  int s1 = s0 + gcnt[b];
  for (int j = s0 + t; j < s1; j += 512)
    atomicAdd(&dl[((unsigned)tmp[j]) >> 16], 1);
  __syncthreads();
  int dv = dl[t], orig = dv;
#pragma unroll
  for (int o = 1; o < 64; o <<= 1) {
    int u = __shfl_up(dv, o, 64);
    if (lane >= o) dv += u;
  }
  if (lane == 63) ws[w] = dv;
  __syncthreads();
  if (t == 0) {
    int a = 0;
#pragma unroll
    for (int k = 0; k < 8; ++k) { int x = ws[k]; ws[k] = a; a += x; }
  }
  __syncthreads();
  int ex = ws[w] + dv - orig;
  cl[t] = ex;
  int node = (b << BSH) + t;
  if (node < n) {
    rowptr[node] = s0 + ex;
    dinv[node] = rsqrtf((float)(orig + 1));  // +1 self loop
  }
  if (b == kb - 1 && t == 0) rowptr[n] = e;
  __syncthreads();
  for (int j = s0 + t; j < s1; j += 512) {
    int p = tmp[j];
    int r = atomicAdd(&cl[((unsigned)p) >> 16], 1);
    colarr[s0 + r] = (unsigned short)(p & 0xFFFF);
  }
}

// out16[i,:] = fp16(relu(dinv[i] * (g[i,:] + sum g[col[e],:]) + bias))
// Clean R11 gather loop (no per-edge scale): uint4 lanes, 16 lanes x 16B =
// 256B row, 4 edge subgroups, 4-deep unroll = 16 edges in flight.
__global__ __launch_bounds__(256) void k_agg_h(
    const __half2* __restrict__ g2, const float* __restrict__ dinv,
    const int* __restrict__ rowptr, const unsigned short* __restrict__ col,
    const float* __restrict__ bias, __half* __restrict__ out16, int n) {
  int i = blockIdx.x * 4 + (threadIdx.x >> 6);
  if (i >= n) return;
  int lane = threadIdx.x & 63;
  int sub = lane >> 4;
  int c8 = lane & 15;
  const uint4* G = (const uint4*)g2;
  float4 z = make_float4(0.f, 0.f, 0.f, 0.f);
  float4 lo0 = z, lo1 = z, lo2 = z, lo3 = z, hi0 = z, hi1 = z, hi2 = z, hi3 = z;
  if (sub == 0) acc8(G[(size_t)i * 16 + c8], lo0, hi0);  // self loop once
  int beg = rowptr[i], end = rowptr[i + 1];
  int j = beg;
  for (; j + 16 <= end; j += 16) {
    int s0 = __builtin_nontemporal_load(&col[j + sub]);
    int s1 = __builtin_nontemporal_load(&col[j + 4 + sub]);
    int s2 = __builtin_nontemporal_load(&col[j + 8 + sub]);
    int s3 = __builtin_nontemporal_load(&col[j + 12 + sub]);
    uint4 u0 = G[(size_t)s0 * 16 + c8];
    uint4 u1 = G[(size_t)s1 * 16 + c8];
    uint4 u2 = G[(size_t)s2 * 16 + c8];
    uint4 u3 = G[(size_t)s3 * 16 + c8];
    acc8(u0, lo0, hi0); acc8(u1, lo1, hi1);
    acc8(u2, lo2, hi2); acc8(u3, lo3, hi3);
  }
  for (; j + 4 <= end; j += 4) {
    int s0 = __builtin_nontemporal_load(&col[j + sub]);
    acc8(G[(size_t)s0 * 16 + c8], lo1, hi1);
  }
  int rem = end - j;
  if (sub < rem) {
    int s0 = __builtin_nontemporal_load(&col[j + sub]);
    acc8(G[(size_t)s0 * 16 + c8], lo2, hi2);
  }
  float4 lo, hi;
  lo.x = (lo0.x + lo1.x) + (lo2.x + lo3.x);
  lo.y = (lo0.y + lo1.y) + (lo2.y + lo3.y);
  lo.z = (lo0.z + lo1.z) + (lo2.z + lo3.z);
  lo.w = (lo0.w + lo1.w) + (lo2.w + lo3.w);
  hi.x = (hi0.x + hi1.x) + (hi2.x + hi3.x);
  hi.y = (hi0.y + hi1.y) + (hi2.y + hi3.y);
  hi.z = (hi0.z + hi1.z) + (hi2.z + hi3.z);
  hi.w = (hi0.w + hi1.w) + (hi2.w + hi3.w);
  lo.x += __shfl_down(lo.x, 32, 64); lo.x += __shfl_down(lo.x, 16, 64);
  lo.y += __shfl_down(lo.y, 32, 64); lo.y += __shfl_down(lo.y, 16, 64);
  lo.z += __shfl_down(lo.z, 32, 64); lo.z += __shfl_down(lo.z, 16, 64);
  lo.w += __shfl_down(lo.w, 32, 64); lo.w += __shfl_down(lo.w, 16, 64);
  hi.x += __shfl_down(hi.x, 32, 64); hi.x += __shfl_down(hi.x, 16, 64);
  hi.y += __shfl_down(hi.y, 32, 64); hi.y += __shfl_down(hi.y, 16, 64);
  hi.z += __shfl_down(hi.z, 32, 64); hi.z += __shfl_down(hi.z, 16, 64);
  hi.w += __shfl_down(hi.w, 32, 64); hi.w += __shfl_down(hi.w, 16, 64);
  if (sub == 0) {
    float di = dinv[i];
    float4 b0 = ((const float4*)bias)[2 * c8];
    float4 b1 = ((const float4*)bias)[2 * c8 + 1];
    __half2 q0 = __floats2half2_rn(fmaxf(fmaf(di, lo.x, b0.x), 0.f),
                                   fmaxf(fmaf(di, lo.y, b0.y), 0.f));
    __half2 q1 = __floats2half2_rn(fmaxf(fmaf(di, lo.z, b0.z), 0.f),
                                   fmaxf(fmaf(di, lo.w, b0.w), 0.f));
    __half2 q2 = __floats2half2_rn(fmaxf(fmaf(di, hi.x, b1.x), 0.f),
                                   fmaxf(fmaf(di, hi.y, b1.y), 0.f));
    __half2 q3 = __floats2half2_rn(fmaxf(fmaf(di, hi.z, b1.z), 0.f),
                                   fmaxf(fmaf(di, hi.w, b1.w), 0.f));
    uint4 o;
    o.x = *(unsigned*)&q0; o.y = *(unsigned*)&q1;
    o.z = *(unsigned*)&q2; o.w = *(unsigned*)&q3;
    ((uint4*)out16)[(size_t)i * 16 + c8] = o;
  }
}

// one wave per pair: sub0 loads A[p0] half4, sub1 loads B[p1] half4;
// combine via shfl_xor(32), dot with wh2, reduce.
__global__ __launch_bounds__(256) void k_pairs_h(
    const __half2* __restrict__ A, const __half2* __restrict__ B,
    const int* __restrict__ pairs, const float* __restrict__ bh1,
    const float* __restrict__ wh2, const float* __restrict__ bh2,
    float* __restrict__ out, int P) {
  int p = blockIdx.x * 4 + (threadIdx.x >> 6);
  int lane = threadIdx.x & 63;
  if (p >= P) return;
  int sub = lane >> 5, c4 = lane & 31;
  int p0 = pairs[2 * p], p1 = pairs[2 * p + 1];
  const uint2* T4 = sub ? (const uint2*)B : (const uint2*)A;
  int row = sub ? p1 : p0;
  float4 v = h4_to_f4(T4[(size_t)row * 32 + c4]);
  v.x += __shfl_xor(v.x, 32, 64);
  v.y += __shfl_xor(v.y, 32, 64);
  v.z += __shfl_xor(v.z, 32, 64);
  v.w += __shfl_xor(v.w, 32, 64);
  float4 bi = ((const float4*)bh1)[c4];
  float4 wv = ((const float4*)wh2)[c4];
  float s = fmaxf(v.x + bi.x, 0.f) * wv.x + fmaxf(v.y + bi.y, 0.f) * wv.y +
            fmaxf(v.z + bi.z, 0.f) * wv.z + fmaxf(v.w + bi.w, 0.f) * wv.w;
#pragma unroll
  for (int o = 16; o > 0; o >>= 1) s += __shfl_down(s, o, 64);
  if (lane == 0) out[p] = s + bh2[0];
}

extern "C" void kernel_launch(void* const* d_in, const int* in_sizes, int n_in,
                              void* d_out, int out_size, void* d_ws, size_t ws_size,
                              hipStream_t stream) {
  const float* x   = (const float*)d_in[0];
  const int* ei    = (const int*)d_in[1];
  const int* pairs = (const int*)d_in[2];
  const float* W1  = (const float*)d_in[3];
  const float* b1  = (const float*)d_in[4];
  const float* W2  = (const float*)d_in[5];
  const float* b2  = (const float*)d_in[6];
  const float* Wh1 = (const float*)d_in[7];
  const float* bh1 = (const float*)d_in[8];
  const float* Wh2 = (const float*)d_in[9];
  const float* bh2 = (const float*)d_in[10];
  (void)n_in; (void)out_size; (void)ws_size;

  int N = in_sizes[0] / 128;
  int E = in_sizes[1] / 2;
  int P = in_sizes[2] / 2;
  const int* src = ei;
  const int* dst = ei + E;
  int KB = (N + BSZ - 1) >> BSH;  // buckets (98 for N=50000)

  char* wsp = (char*)d_ws;
  size_t off = 0;
  auto alloc = [&](size_t bytes) -> void* {
    void* p = wsp + off;
    off += (bytes + 255) & ~(size_t)255;
    return p;
  };
  __half* g16 = (__half*)alloc((size_t)N * 128 * 2);  // messages; reused as A16
  __half* h1  = (__half*)alloc((size_t)N * 128 * 2);  // fp16; reused as B16
  __half* h2  = (__half*)alloc((size_t)N * 128 * 2);  // fp16
  float* dinv = (float*)alloc((size_t)N * 4);
  int* rowptr = (int*)alloc((size_t)(N + 1) * 4);
  unsigned short* colarr = (unsigned short*)alloc((size_t)E * 2);
  int* tmp    = (int*)alloc((size_t)E * 4);
  short* fragH = (short*)alloc(4 * 2048 * 8 * 2);     // 128KB
  short* fragL = (short*)alloc(4 * 2048 * 8 * 2);     // 128KB
  int* gcnt  = (int*)alloc((size_t)(KB + 1) * 4);
  int* gcur  = (int*)alloc((size_t)(KB + 1) * 4);
  __half* A16 = g16;            // g16 dead by the time head runs
  __half* B16 = h1;             // h1 dead after conv2 gemm
  short* fH_W1 = fragH + 0 * 16384;  short* fL_W1 = fragL + 0 * 16384;
  short* fH_W2 = fragH + 1 * 16384;  short* fL_W2 = fragL + 1 * 16384;
  short* fH_Wa = fragH + 2 * 16384;  short* fL_Wa = fragL + 2 * 16384;
  short* fH_Wb = fragH + 3 * 16384;  short* fL_Wb = fragL + 3 * 16384;

  int GB = (N + 63) / 64;          // fp32 gemm: 64 rows per block
  int GF = (N / 16 + 3) / 4;       // f16 gemm: 16 rows/wave, 4 waves/block
  int AB = (N + 3) / 4;            // agg: 4 rows per block

  // zero bucket counters (graph-capture-safe), then fused prep+hist
  hipMemsetAsync(gcnt, 0, (size_t)(KB + 1) * 4, stream);
  hipMemsetAsync(gcur, 0, (size_t)(KB + 1) * 4, stream);
  k_prep_hist<<<32 + HB, 256, 0, stream>>>(W1, W2, Wh1, fragH, fragL,
                                           dst, gcnt, E, KB);
  // CSR build
  k_multisplit<<<(E + MSB - 1) / MSB, 256, 0, stream>>>(src, dst, gcnt, gcur,
                                                        tmp, E, KB);
  k_bucket_build<<<KB, 512, 0, stream>>>(tmp, gcnt, rowptr, dinv, colarr, N, KB, E);
  // conv1 (gemm pre-scales with dinv -> clean agg loops)
  k_gemm_mfma<<<GB, 256, 0, stream>>>(x, fH_W1, fL_W1, dinv, g16, N);
  k_agg_h<<<AB, 256, 0, stream>>>((const __half2*)g16, dinv, rowptr, colarr, b1, h1, N);
  // conv2 (f16 path)
  k_gemm_f16<<<GF, 256, 0, stream>>>(h1, fH_W2, fL_W2, dinv, g16, N);
  k_agg_h<<<AB, 256, 0, stream>>>((const __half2*)g16, dinv, rowptr, colarr, b2, h2, N);
  // head
  k_gemm_dual_f16<<<GF, 256, 0, stream>>>(h2, fH_Wa, fL_Wa, fH_Wb, fL_Wb,
                                          A16, B16, N);
  k_pairs_h<<<(P + 3) / 4, 256, 0, stream>>>((const __half2*)A16, (const __half2*)B16,
                                             pairs, bh1, Wh2, bh2, (float*)d_out, P);
}